// Round 1
// 403.222 us; speedup vs baseline: 1.0629x; 1.0629x over previous
//
#include <hip/hip_runtime.h>
#include <hip/hip_bf16.h>
#include <stdint.h>

// Problem dims (fixed by reference setup_inputs)
#define Mdim 8192   // B*S = 4*2048
#define Ndim 4096   // OUT
#define Kdim 4096   // IN

// GEMM tile geometry: 256x256 tile, BK=128 (two K=64 slices), 8 waves.
#define BM 256
#define BN 256
#define BK 128

typedef int v4i __attribute__((ext_vector_type(4)));

__device__ __forceinline__ void gload_lds16(const void* g, void* l) {
  __builtin_amdgcn_global_load_lds(
      (const __attribute__((address_space(1))) unsigned int*)g,
      (__attribute__((address_space(3))) unsigned int*)l,
      16 /*bytes*/, 0 /*offset*/, 0 /*aux*/);
}

// ---------------------------------------------------------------------------
// Kernel 1: quantize activations. xi = clip(rint((x*input_scale)*(1/act)))
// ---------------------------------------------------------------------------
__global__ void quant_x_kernel(const float* __restrict__ x,
                               const float* __restrict__ in_scale,
                               const float* __restrict__ act_scale_p,
                               int8_t* __restrict__ xq) {
  const float inv_act = 1.0f / (*act_scale_p);
  const int64_t tid = (int64_t)blockIdx.x * blockDim.x + threadIdx.x;
  const int64_t base = tid * 16;
  const int k0 = (int)(base & (Kdim - 1));  // Kdim is pow2
  const float4* xv = (const float4*)(x + base);
  const float4* sv = (const float4*)(in_scale + k0);
  alignas(16) int8_t ob[16];
#pragma unroll
  for (int j = 0; j < 4; ++j) {
    float4 xx = xv[j];
    float4 ss = sv[j];
    float r0 = rintf((xx.x * ss.x) * inv_act);
    float r1 = rintf((xx.y * ss.y) * inv_act);
    float r2 = rintf((xx.z * ss.z) * inv_act);
    float r3 = rintf((xx.w * ss.w) * inv_act);
    r0 = fminf(fmaxf(r0, -127.f), 127.f);
    r1 = fminf(fmaxf(r1, -127.f), 127.f);
    r2 = fminf(fmaxf(r2, -127.f), 127.f);
    r3 = fminf(fmaxf(r3, -127.f), 127.f);
    ob[j * 4 + 0] = (int8_t)r0;
    ob[j * 4 + 1] = (int8_t)r1;
    ob[j * 4 + 2] = (int8_t)r2;
    ob[j * 4 + 3] = (int8_t)r3;
  }
  *(v4i*)(xq + base) = *(const v4i*)ob;
}

// ---------------------------------------------------------------------------
// Kernel 2: pack int32 weights to int8 ([N,K] row-major kept as-is = B^T).
// ---------------------------------------------------------------------------
__global__ void pack_w_kernel(const int* __restrict__ w, int8_t* __restrict__ wq) {
  const int64_t tid = (int64_t)blockIdx.x * blockDim.x + threadIdx.x;
  const int64_t base = tid * 16;
  const int4* wv = (const int4*)(w + base);
  alignas(16) int8_t ob[16];
#pragma unroll
  for (int j = 0; j < 4; ++j) {
    int4 t = wv[j];
    ob[j * 4 + 0] = (int8_t)t.x;
    ob[j * 4 + 1] = (int8_t)t.y;
    ob[j * 4 + 2] = (int8_t)t.z;
    ob[j * 4 + 3] = (int8_t)t.w;
  }
  *(v4i*)(wq + base) = *(const v4i*)ob;
}

// ---------------------------------------------------------------------------
// Kernel 3: int8 GEMM, 256^2 8-phase schedule (T3+T4+T5 port of the verified
// bf16 template). C[M,N] = Aq[M,K] . Bq[N,K]^T
//
// - 512 threads = 8 waves (2M x 4N); wave owns 128x64 C; 8x4 mfma 16x16x64.
// - LDS 128 KiB: [2 dbuf][2 k-slices] x (A 256x64B + B 256x64B), the proven
//   64B-row XOR-swizzled layout (phys_chunk = logical ^ ((row>>1)&3)),
//   pre-swizzled GLOBAL source + linear global_load_lds dest -> 0 conflicts.
// - Per K-tile: 4 phases {ds_read subtile | 2 gload_lds prefetch | s_barrier |
//   lgkmcnt(0) | setprio(1) 16 MFMA setprio(0) | barrier}. Counted vmcnt(4)
//   ONLY at phases 1 and 3 (drains exactly the k-slice about to be read,
//   leaves 4 prefetch loads in flight). Never vmcnt(0) in the main loop.
// - Last tile issues a dummy wrap prefetch (tile 0, L3-hot, dead buffer) so
//   vmcnt accounting stays uniform.
// ---------------------------------------------------------------------------
#define PBAR()                        \
  do {                                \
    asm volatile("" ::: "memory");    \
    __builtin_amdgcn_s_barrier();     \
    asm volatile("" ::: "memory");    \
  } while (0)
#define LGKM0() asm volatile("s_waitcnt lgkmcnt(0)" ::: "memory")
#define VMCNT(n) asm volatile("s_waitcnt vmcnt(" #n ")" ::: "memory")

#define MFMA16(mh)                                                        \
  do {                                                                    \
    __builtin_amdgcn_s_setprio(1);                                        \
    _Pragma("unroll") for (int i = 0; i < 4; ++i) {                       \
      _Pragma("unroll") for (int j = 0; j < 4; ++j) {                     \
        acc[(mh) * 4 + i][j] = __builtin_amdgcn_mfma_i32_16x16x64_i8(     \
            af[i], bf[j], acc[(mh) * 4 + i][j], 0, 0, 0);                 \
      }                                                                   \
    }                                                                     \
    __builtin_amdgcn_s_setprio(0);                                        \
  } while (0)

__global__ __launch_bounds__(512, 2) void gemm_i8_kernel(
    const int8_t* __restrict__ Aq, const int8_t* __restrict__ Bq,
    const float* __restrict__ w_scale, const float* __restrict__ bias,
    const float* __restrict__ act_scale_p, float* __restrict__ out) {
  __shared__ alignas(16) int8_t As[2][2][BM * 64];  // [buf][kslice] 4x16KB
  __shared__ alignas(16) int8_t Bs[2][2][BN * 64];

  const int t = threadIdx.x;

  // Grid 512 = 32 m-blocks x 16 n-blocks; 2-wide m supertile for B reuse.
  const int lin = blockIdx.x;
  const int within = lin & 31;
  const int m_blk = (lin >> 5) * 2 + (within & 1);  // 0..31
  const int n_blk = within >> 1;                    // 0..15
  const int m0 = m_blk * BM;
  const int n0 = n_blk * BN;

  // Staging: thread t fills LDS slot t*16 (row = t>>2 in half h, phys chunk
  // = (t&3) ^ ((row>>1)&3) applied to the GLOBAL source address).
  const int srow = t >> 2;                            // 0..127
  const int scol = ((t & 3) ^ ((t >> 3) & 3)) * 16;   // swizzled k-offset
  const int8_t* gA0 = Aq + (int64_t)(m0 + srow) * Kdim + scol;  // rows 0-127
  const int8_t* gA1 = gA0 + (int64_t)128 * Kdim;                // rows 128-255
  const int8_t* gB0 = Bq + (int64_t)(n0 + srow) * Kdim + scol;
  const int8_t* gB1 = gB0 + (int64_t)128 * Kdim;
  const int ldst = t * 16;

  const int w = t >> 6;           // wave 0..7
  const int l = t & 63;           // lane
  const int wm = (w >> 2) * 128;  // wave C-rows origin within tile (2M)
  const int wn = (w & 3) * 64;    // wave C-cols origin within tile (4N)
  const int lrow = l & 15;        // fragment row (m for A, n for B)
  const int lk = ((l >> 4) ^ ((l >> 1) & 3)) * 16;  // swizzled phys chunk
  const int abase = (wm + lrow) * 64 + lk;
  const int bbase = (wn + lrow) * 64 + lk;

  v4i acc[8][4] = {};

#define STG(MAT, buf, ks, h, koff) \
  gload_lds16(g##MAT##h + (koff) + (ks) * 64, &MAT##s[buf][ks][(h) * 8192 + ldst])

  // Prologue: stage tile 0 into buf 0 (order: ks0 h0, ks0 h1, ks1 h0, ks1 h1)
  STG(A, 0, 0, 0, 0); STG(B, 0, 0, 0, 0);
  STG(A, 0, 0, 1, 0); STG(B, 0, 0, 1, 0);
  STG(A, 0, 1, 0, 0); STG(B, 0, 1, 0, 0);
  STG(A, 0, 1, 1, 0); STG(B, 0, 1, 1, 0);
  VMCNT(4);  // k-slice 0 landed; slice 1's 4 loads stay in flight
  PBAR();

  for (int kt = 0; kt < Kdim; kt += BK) {
    const int cur = (kt >> 7) & 1;
    const int nxt = cur ^ 1;
    int kn = kt + BK;
    if (kn >= Kdim) kn = 0;  // dummy wrap: keeps vmcnt counts uniform

    v4i af[4], bf[4];

    // ---- phase 0: ks=0, mh=0 ----
#pragma unroll
    for (int j = 0; j < 4; ++j) bf[j] = *(const v4i*)&Bs[cur][0][bbase + j * 1024];
#pragma unroll
    for (int i = 0; i < 4; ++i) af[i] = *(const v4i*)&As[cur][0][abase + i * 1024];
    STG(A, nxt, 0, 0, kn); STG(B, nxt, 0, 0, kn);
    PBAR(); LGKM0();
    MFMA16(0);
    PBAR();

    // ---- phase 1: ks=0, mh=1 ----
#pragma unroll
    for (int i = 0; i < 4; ++i) af[i] = *(const v4i*)&As[cur][0][abase + 4096 + i * 1024];
    STG(A, nxt, 0, 1, kn); STG(B, nxt, 0, 1, kn);
    PBAR(); LGKM0();
    MFMA16(1);
    VMCNT(4);  // drain this tile's k-slice 1; 4 prefetch loads in flight
    PBAR();

    // ---- phase 2: ks=1, mh=0 ----
#pragma unroll
    for (int j = 0; j < 4; ++j) bf[j] = *(const v4i*)&Bs[cur][1][bbase + j * 1024];
#pragma unroll
    for (int i = 0; i < 4; ++i) af[i] = *(const v4i*)&As[cur][1][abase + i * 1024];
    STG(A, nxt, 1, 0, kn); STG(B, nxt, 1, 0, kn);
    PBAR(); LGKM0();
    MFMA16(0);
    PBAR();

    // ---- phase 3: ks=1, mh=1 ----
#pragma unroll
    for (int i = 0; i < 4; ++i) af[i] = *(const v4i*)&As[cur][1][abase + 4096 + i * 1024];
    STG(A, nxt, 1, 1, kn); STG(B, nxt, 1, 1, kn);
    PBAR(); LGKM0();
    MFMA16(1);
    VMCNT(4);  // drain next tile's k-slice 0; its slice 1 stays in flight
    PBAR();
  }
  VMCNT(0);  // drain dummy prefetch before LDS teardown

  // Epilogue: D mapping col = lane&15, row = (lane>>4)*4 + reg
  const float act = *act_scale_p;
  const int rowbase = (l >> 4) * 4;
#pragma unroll
  for (int j = 0; j < 4; ++j) {
    const int n = n0 + wn + j * 16 + lrow;
    const float sc = act * w_scale[n];
    const float bs = bias[n];
#pragma unroll
    for (int i = 0; i < 8; ++i) {
      const int mb = m0 + wm + i * 16 + rowbase;
#pragma unroll
      for (int r = 0; r < 4; ++r) {
        out[(int64_t)(mb + r) * Ndim + n] = (float)acc[i][j][r] * sc + bs;
      }
    }
  }
}

// ---------------------------------------------------------------------------
extern "C" void kernel_launch(void* const* d_in, const int* in_sizes, int n_in,
                              void* d_out, int out_size, void* d_ws, size_t ws_size,
                              hipStream_t stream) {
  const float* x        = (const float*)d_in[0];
  const float* in_scale = (const float*)d_in[1];
  const float* actp     = (const float*)d_in[2];
  const int*   w_int    = (const int*)d_in[3];
  const float* w_scale  = (const float*)d_in[4];
  const float* bias     = (const float*)d_in[5];
  float* out = (float*)d_out;

  int8_t* Aq = (int8_t*)d_ws;                        // 32 MiB
  int8_t* Bq = (int8_t*)d_ws + (size_t)Mdim * Kdim;  // 16 MiB

  {
    const int64_t nthreads = (int64_t)Mdim * Kdim / 16;  // 2,097,152
    quant_x_kernel<<<(int)(nthreads / 256), 256, 0, stream>>>(x, in_scale, actp, Aq);
  }
  {
    const int64_t nthreads = (int64_t)Ndim * Kdim / 16;  // 1,048,576
    pack_w_kernel<<<(int)(nthreads / 256), 256, 0, stream>>>(w_int, Bq);
  }
  {
    gemm_i8_kernel<<<dim3(512), 512, 0, stream>>>(Aq, Bq, w_scale, bias, actp, out);
  }
}